// Round 10
// baseline (642.315 us; speedup 1.0000x reference)
//
#include <hip/hip_runtime.h>

#define D 128

__device__ __forceinline__ unsigned short f2bf(float f) {
    union { float f; unsigned u; } c; c.f = f;
    unsigned u = c.u;
    return (unsigned short)((u + 0x7fffu + ((u >> 16) & 1u)) >> 16);  // RN
}
__device__ __forceinline__ float bf2f(unsigned short s) {
    union { unsigned u; float f; } c; c.u = ((unsigned)s) << 16;
    return c.f;
}

// ---------------------------------------------------------------------------
// CSR build, single-pass bucketize:
//   k_bucket: one pass over edges; rank edges into <=16 dst-range shards
//             (shard = dst >> shift) via LDS atomics; write (dst,src) pairs
//             into per-shard segments. 12.8MB read + 12.8MB write, once.
//   k_hist2 / k_fill2: per-shard blocks (blockIdx&15 -> XCD-local atomics)
//             process 8 edges/thread with batched independent atomics.
// ---------------------------------------------------------------------------

__global__ __launch_bounds__(256) void k_bucket(const int* __restrict__ dst,
                                                const int* __restrict__ src,
                                                int2* __restrict__ pairs,
                                                int* __restrict__ shard_total,
                                                int e, int shift, int cap) {
    __shared__ int cnt[16], base[16];
    if (threadIdx.x < 16) cnt[threadIdx.x] = 0;
    __syncthreads();
    int i4    = blockIdx.x * 256 + threadIdx.x;
    int ebase = i4 * 4;
    int nown  = min(4, e - ebase);  // may be <=0
    int dd[4], ss[4], sh[4], rk[4];
    if (nown == 4) {
        int4 d = ((const int4*)dst)[i4];
        int4 s = ((const int4*)src)[i4];
        dd[0] = d.x; dd[1] = d.y; dd[2] = d.z; dd[3] = d.w;
        ss[0] = s.x; ss[1] = s.y; ss[2] = s.z; ss[3] = s.w;
    } else {
        for (int j = 0; j < nown; ++j) { dd[j] = dst[ebase + j]; ss[j] = src[ebase + j]; }
    }
    for (int j = 0; j < nown; ++j) {
        sh[j] = dd[j] >> shift;
        rk[j] = atomicAdd(&cnt[sh[j]], 1);
    }
    __syncthreads();
    if (threadIdx.x < 16)
        base[threadIdx.x] = atomicAdd(&shard_total[threadIdx.x], cnt[threadIdx.x]);
    __syncthreads();
    for (int j = 0; j < nown; ++j) {
        int pos = base[sh[j]] + rk[j];
        if (pos < cap) pairs[(size_t)sh[j] * cap + pos] = int2{dd[j], ss[j]};
    }
}

__global__ __launch_bounds__(256) void k_hist2(const int2* __restrict__ pairs,
                                               const int* __restrict__ shard_total,
                                               int* __restrict__ degi,
                                               int cap, int ns) {
    int s = blockIdx.x & 15;
    if (s >= ns) return;
    int cnt = min(shard_total[s], cap);
    const int2* seg = pairs + (size_t)s * cap;
    int bi = ((blockIdx.x >> 4) * 256 + threadIdx.x) * 8;
    int nr = min(8, cnt - bi);
    if (nr <= 0) return;
    int v[8];
    if (nr == 8) {
#pragma unroll
        for (int j = 0; j < 8; ++j) v[j] = seg[bi + j].x;
#pragma unroll
        for (int j = 0; j < 8; ++j) atomicAdd(&degi[v[j]], 1);
    } else {
        for (int j = 0; j < nr; ++j) v[j] = seg[bi + j].x;
        for (int j = 0; j < nr; ++j) atomicAdd(&degi[v[j]], 1);
    }
}

__global__ __launch_bounds__(256) void k_fill2(const int2* __restrict__ pairs,
                                               const int* __restrict__ shard_total,
                                               int* __restrict__ cursor,
                                               int* __restrict__ col,
                                               int cap, int ns) {
    int s = blockIdx.x & 15;
    if (s >= ns) return;
    int cnt = min(shard_total[s], cap);
    const int2* seg = pairs + (size_t)s * cap;
    int bi = ((blockIdx.x >> 4) * 256 + threadIdx.x) * 8;
    int nr = min(8, cnt - bi);
    if (nr <= 0) return;
    int2 p[8];
    int pos[8];
    if (nr == 8) {
#pragma unroll
        for (int j = 0; j < 8; ++j) p[j] = seg[bi + j];
#pragma unroll
        for (int j = 0; j < 8; ++j) pos[j] = atomicAdd(&cursor[p[j].x], 1);
#pragma unroll
        for (int j = 0; j < 8; ++j) col[pos[j]] = p[j].y;
    } else {
        for (int j = 0; j < nr; ++j) p[j] = seg[bi + j];
        for (int j = 0; j < nr; ++j) pos[j] = atomicAdd(&cursor[p[j].x], 1);
        for (int j = 0; j < nr; ++j) col[pos[j]] = p[j].y;
    }
}

// Per-block exclusive scan of 1024 elements (256 thr x 4), also computes
// dis[v] = rsqrt(deg_real + 1)  (the +1 is the self-loop).
__global__ __launch_bounds__(256) void k_scan_local(const int* __restrict__ degi,
                                                    int* __restrict__ rowptr,
                                                    int* __restrict__ blocksums,
                                                    float* __restrict__ dis, int n) {
    __shared__ int sd[256];
    int tid  = threadIdx.x;
    int base = blockIdx.x * 1024 + tid * 4;
    int v0 = 0, v1 = 0, v2 = 0, v3 = 0;
    if (base + 0 < n) v0 = degi[base + 0];
    if (base + 1 < n) v1 = degi[base + 1];
    if (base + 2 < n) v2 = degi[base + 2];
    if (base + 3 < n) v3 = degi[base + 3];
    if (base + 0 < n) dis[base + 0] = rsqrtf((float)(v0 + 1));
    if (base + 1 < n) dis[base + 1] = rsqrtf((float)(v1 + 1));
    if (base + 2 < n) dis[base + 2] = rsqrtf((float)(v2 + 1));
    if (base + 3 < n) dis[base + 3] = rsqrtf((float)(v3 + 1));
    int tsum = v0 + v1 + v2 + v3;
    sd[tid] = tsum;
    __syncthreads();
    for (int off = 1; off < 256; off <<= 1) {
        int add = (tid >= off) ? sd[tid - off] : 0;
        __syncthreads();
        sd[tid] += add;
        __syncthreads();
    }
    int incl = sd[tid];
    int excl = incl - tsum;
    if (tid == 255) blocksums[blockIdx.x] = incl;
    if (base + 0 < n) rowptr[base + 0] = excl;
    if (base + 1 < n) rowptr[base + 1] = excl + v0;
    if (base + 2 < n) rowptr[base + 2] = excl + v0 + v1;
    if (base + 3 < n) rowptr[base + 3] = excl + v0 + v1 + v2;
}

__global__ __launch_bounds__(128) void k_scan_bsum(int* __restrict__ bs, int nb) {
    __shared__ int sd[128];
    int t = threadIdx.x;
    int v = (t < nb) ? bs[t] : 0;
    sd[t] = v;
    __syncthreads();
    for (int off = 1; off < 128; off <<= 1) {
        int add = (t >= off) ? sd[t - off] : 0;
        __syncthreads();
        sd[t] += add;
        __syncthreads();
    }
    if (t < nb) bs[t] = sd[t] - v;  // exclusive
}

__global__ __launch_bounds__(256) void k_scan_add(int* __restrict__ rowptr,
                                                  int* __restrict__ cursor,
                                                  const int* __restrict__ blocksums,
                                                  int n, int total) {
    int i = blockIdx.x * 256 + threadIdx.x;
    if (i < n) {
        int r = rowptr[i] + blocksums[i >> 10];
        rowptr[i] = r;
        cursor[i] = r;
    }
    if (i == 0) rowptr[n] = total;
}

// ---------------------------------------------------------------------------
// h_bf16 = bf16( dis[v] * (x @ W[l]) ).
// W (64KB fp32) + 32-row x tile (16KB) in LDS -> 80KB, 2 blocks/CU.
// Thread computes 4 rows x 4 cols (float4 acc): per k4 the wave issues
// 4 x-reads + 4 W-reads (all ds_read_b128, 2-way broadcast = free) feeding
// 128 FMAs/thread -> VALU-bound. Register-prefetch double buffer.
// ---------------------------------------------------------------------------
__global__ __launch_bounds__(256) void k_gemm(const float* __restrict__ x,
                                              const float* __restrict__ W,
                                              const float* __restrict__ dis,
                                              unsigned short* __restrict__ h, int n) {
    extern __shared__ float smem[];
    float4* Ws4 = (float4*)smem;            // [128 k][32 col-groups]
    float4* xs4 = (float4*)(smem + D * D);  // [32 rows][32 k-groups]
    {
        const float4* W4 = (const float4*)W;
#pragma unroll
        for (int i = 0; i < 16; ++i)
            Ws4[threadIdx.x + i * 256] = W4[threadIdx.x + i * 256];
    }
    int wave  = threadIdx.x >> 6;
    int lane  = threadIdx.x & 63;
    int rbase = wave * 8 + (lane >> 5) * 4;  // local row base (4 rows)
    int cg    = lane & 31;                   // col-group (4 cols)

    const float4* X4 = (const float4*)x;
    size_t n4     = (size_t)n * (D / 4);
    int    ntiles = (n + 31) / 32;

    int    tile = blockIdx.x;
    float4 pf[4];
    {   // prefetch tile 0
        size_t base4 = (size_t)tile * 32 * (D / 4);
#pragma unroll
        for (int j = 0; j < 4; ++j) {
            size_t gi = base4 + threadIdx.x + j * 256;
            pf[j] = (tile < ntiles && gi < n4) ? X4[gi] : float4{0.f, 0.f, 0.f, 0.f};
        }
    }
    __syncthreads();  // W staged

    for (; tile < ntiles; tile += gridDim.x) {
#pragma unroll
        for (int j = 0; j < 4; ++j) xs4[threadIdx.x + j * 256] = pf[j];
        __syncthreads();

        int nt = tile + gridDim.x;  // issue next tile's loads (in flight all compute)
        if (nt < ntiles) {
            size_t base4 = (size_t)nt * 32 * (D / 4);
#pragma unroll
            for (int j = 0; j < 4; ++j) {
                size_t gi = base4 + threadIdx.x + j * 256;
                if (gi < n4) pf[j] = X4[gi];
            }
        }

        float4 acc[4];
#pragma unroll
        for (int r = 0; r < 4; ++r) acc[r] = float4{0.f, 0.f, 0.f, 0.f};

#pragma unroll 4
        for (int k4 = 0; k4 < 32; ++k4) {
            float4 xr[4];
#pragma unroll
            for (int r = 0; r < 4; ++r) xr[r] = xs4[(rbase + r) * 32 + k4];
            float4 wv[4];
#pragma unroll
            for (int i = 0; i < 4; ++i) wv[i] = Ws4[(4 * k4 + i) * 32 + cg];
#pragma unroll
            for (int i = 0; i < 4; ++i) {
#pragma unroll
                for (int r = 0; r < 4; ++r) {
                    float e = (&xr[r].x)[i];
                    acc[r].x = fmaf(e, wv[i].x, acc[r].x);
                    acc[r].y = fmaf(e, wv[i].y, acc[r].y);
                    acc[r].z = fmaf(e, wv[i].z, acc[r].z);
                    acc[r].w = fmaf(e, wv[i].w, acc[r].w);
                }
            }
        }

        int grow = tile * 32 + rbase;
        ushort4* h4 = (ushort4*)h;  // row = 32 ushort4 (4 bf16 each)
#pragma unroll
        for (int r = 0; r < 4; ++r) {
            int row = grow + r;
            if (row < n) {
                float dv = dis[row];
                ushort4 o;
                o.x = f2bf(acc[r].x * dv);
                o.y = f2bf(acc[r].y * dv);
                o.z = f2bf(acc[r].z * dv);
                o.w = f2bf(acc[r].w * dv);
                h4[(size_t)row * 32 + cg] = o;
            }
        }
        __syncthreads();  // xs free for next iteration's store
    }
}

// ---------------------------------------------------------------------------
// out[v] = relu( dis[v] * (hs[v] + sum_{s in N(v)} hs[s]) + b )
// h is bf16: row = 256B = 32 lanes x ushort4. Half-wave per node, 2 nodes per
// wave, 8-deep unrolled gather (2KB in flight per half-wave). fp32 accum.
// ---------------------------------------------------------------------------
__global__ __launch_bounds__(256) void k_agg(const unsigned short* __restrict__ h,
                                             const int* __restrict__ rowptr,
                                             const int* __restrict__ col,
                                             const float* __restrict__ dis,
                                             const float* __restrict__ b,
                                             float* __restrict__ out, int n) {
    int wave = threadIdx.x >> 6;
    int lane = threadIdx.x & 63;
    int half = lane >> 5;
    int hl   = lane & 31;
    int v = blockIdx.x * 8 + wave * 2 + half;
    if (v >= n) return;
    const ushort4* h4 = (const ushort4*)h;  // row = 32 ushort4

    ushort4 sv = h4[(size_t)v * 32 + hl];
    float ax[4] = {bf2f(sv.x), 0.f, 0.f, 0.f};
    float ay[4] = {bf2f(sv.y), 0.f, 0.f, 0.f};
    float az[4] = {bf2f(sv.z), 0.f, 0.f, 0.f};
    float aw[4] = {bf2f(sv.w), 0.f, 0.f, 0.f};

    int beg = rowptr[v], end = rowptr[v + 1];
    int i = beg;
    for (; i + 8 <= end; i += 8) {
        int c[8];
#pragma unroll
        for (int j = 0; j < 8; ++j) c[j] = col[i + j];
        ushort4 m[8];
#pragma unroll
        for (int j = 0; j < 8; ++j) m[j] = h4[(size_t)c[j] * 32 + hl];
#pragma unroll
        for (int j = 0; j < 8; ++j) {
            int q = j & 3;
            ax[q] += bf2f(m[j].x);
            ay[q] += bf2f(m[j].y);
            az[q] += bf2f(m[j].z);
            aw[q] += bf2f(m[j].w);
        }
    }
    for (; i < end; ++i) {
        ushort4 m = h4[(size_t)col[i] * 32 + hl];
        ax[0] += bf2f(m.x); ay[0] += bf2f(m.y);
        az[0] += bf2f(m.z); aw[0] += bf2f(m.w);
    }

    float  dv = dis[v];
    float4 bb = ((const float4*)b)[hl];
    float4 r;
    r.x = fmaxf(0.f, (ax[0] + ax[1] + ax[2] + ax[3]) * dv + bb.x);
    r.y = fmaxf(0.f, (ay[0] + ay[1] + ay[2] + ay[3]) * dv + bb.y);
    r.z = fmaxf(0.f, (az[0] + az[1] + az[2] + az[3]) * dv + bb.z);
    r.w = fmaxf(0.f, (aw[0] + aw[1] + aw[2] + aw[3]) * dv + bb.w);
    ((float4*)out)[(size_t)v * 32 + hl] = r;
}

// ---------------------------------------------------------------------------

extern "C" void kernel_launch(void* const* d_in, const int* in_sizes, int n_in,
                              void* d_out, int out_size, void* d_ws, size_t ws_size,
                              hipStream_t stream) {
    const float* x0 = (const float*)d_in[0];
    const int*   ei = (const int*)d_in[1];
    const float* W  = (const float*)d_in[2];
    const float* b  = (const float*)d_in[3];

    int n = in_sizes[0] / D;        // 100000
    int e = in_sizes[1] / 2;        // 1600000
    int L = in_sizes[2] / (D * D);  // 3

    const int* srcI = ei;       // edge_index[0] : message source
    const int* dstI = ei + e;   // edge_index[1] : aggregation target

    // shard geometry: shard = dst >> shift, at most 16 shards
    int shift = 13;
    while (((n - 1) >> shift) >= 16) ++shift;
    int ns  = ((n - 1) >> shift) + 1;                          // 13 for n=100000
    int cap = (int)(((long long)e << shift) / (long long)n) + 32768;

    // workspace carve (H first: 25.6MB of bf16, byte offset stays 16B-aligned)
    unsigned short* H = (unsigned short*)d_ws;            // n*128 bf16
    int*   degi        = (int*)(H + (size_t)n * D);       // n
    int*   shard_total = degi + n;                        // 16 (memset with degi)
    int*   rowptr      = shard_total + 16;                // n+1
    int*   cursor      = rowptr + n + 1;                  // n
    float* dis         = (float*)(cursor + n);            // n
    int*   col         = (int*)(dis + n);                 // e
    int*   blocksums   = col + e;                         // 128
    size_t pa = ((size_t)(blocksums + 128) + 15) & ~(size_t)15;
    int2*  pairs       = (int2*)pa;                       // 16*cap int2 (~21MB)

    hipMemsetAsync(degi, 0, (size_t)(n + 16) * sizeof(int), stream);

    int nthreads_b = (e + 3) / 4;
    int nblA = (nthreads_b + 255) / 256;
    k_bucket<<<nblA, 256, 0, stream>>>(dstI, srcI, pairs, shard_total, e, shift, cap);

    k_hist2<<<16 * 128, 256, 0, stream>>>(pairs, shard_total, degi, cap, ns);

    int nscan = (n + 1023) / 1024;  // 98 blocks
    k_scan_local<<<nscan, 256, 0, stream>>>(degi, rowptr, blocksums, dis, n);
    k_scan_bsum<<<1, 128, 0, stream>>>(blocksums, nscan);
    int nb2 = (n + 255) / 256;
    k_scan_add<<<nb2, 256, 0, stream>>>(rowptr, cursor, blocksums, n, e);

    k_fill2<<<16 * 128, 256, 0, stream>>>(pairs, shard_total, cursor, col, cap, ns);

    float*       out = (float*)d_out;
    const float* xin = x0;
    size_t lds_bytes = (size_t)(D * D + 32 * D) * sizeof(float);  // 80 KB
    for (int l = 0; l < L; ++l) {
        k_gemm<<<512, 256, lds_bytes, stream>>>(xin, W + (size_t)l * D * D, dis, H, n);
        k_agg<<<(n + 7) / 8, 256, 0, stream>>>(H, rowptr, col, dis, b + (size_t)l * D, out, n);
        xin = out;
    }
}

// Round 11
// 542.588 us; speedup vs baseline: 1.1838x; 1.1838x over previous
//
#include <hip/hip_runtime.h>

#define D 128

__device__ __forceinline__ unsigned short f2bf(float f) {
    union { float f; unsigned u; } c; c.f = f;
    unsigned u = c.u;
    return (unsigned short)((u + 0x7fffu + ((u >> 16) & 1u)) >> 16);  // RN
}
__device__ __forceinline__ float bf2f(unsigned short s) {
    union { unsigned u; float f; } c; c.u = ((unsigned)s) << 16;
    return c.f;
}

// ---------------------------------------------------------------------------
// CSR build, two-level bucketize + LDS-local hist/fill (no global random
// scatter anywhere):
//   k_bucket : edges -> 16 dst-range shards (coalesced segment writes)
//   k_bucket2: shard segments -> 196 sub-segments of 512 nodes each
//   k_hist_sub: per sub-shard LDS histogram -> degi written SEQUENTIALLY
//   k_fill_sub: per sub-shard LDS sort (scatter hits LDS) -> col written
//               SEQUENTIALLY (full-line coalesced stores)
// ---------------------------------------------------------------------------

__global__ __launch_bounds__(256) void k_bucket(const int* __restrict__ dst,
                                                const int* __restrict__ src,
                                                int2* __restrict__ pairs,
                                                int* __restrict__ shard_total,
                                                int e, int shift, int cap) {
    __shared__ int cnt[16], base[16];
    if (threadIdx.x < 16) cnt[threadIdx.x] = 0;
    __syncthreads();
    int i4    = blockIdx.x * 256 + threadIdx.x;
    int ebase = i4 * 4;
    int nown  = min(4, e - ebase);  // may be <=0
    int dd[4], ss[4], sh[4], rk[4];
    if (nown == 4) {
        int4 d = ((const int4*)dst)[i4];
        int4 s = ((const int4*)src)[i4];
        dd[0] = d.x; dd[1] = d.y; dd[2] = d.z; dd[3] = d.w;
        ss[0] = s.x; ss[1] = s.y; ss[2] = s.z; ss[3] = s.w;
    } else {
        for (int j = 0; j < nown; ++j) { dd[j] = dst[ebase + j]; ss[j] = src[ebase + j]; }
    }
    for (int j = 0; j < nown; ++j) {
        sh[j] = dd[j] >> shift;
        rk[j] = atomicAdd(&cnt[sh[j]], 1);
    }
    __syncthreads();
    if (threadIdx.x < 16 && cnt[threadIdx.x] > 0)
        base[threadIdx.x] = atomicAdd(&shard_total[threadIdx.x], cnt[threadIdx.x]);
    __syncthreads();
    for (int j = 0; j < nown; ++j) {
        int pos = base[sh[j]] + rk[j];
        if (pos < cap) pairs[(size_t)sh[j] * cap + pos] = int2{dd[j], ss[j]};
    }
}

// shard segments -> sub-segments of 512 nodes (sub = (dst>>s2), 16 per shard)
__global__ __launch_bounds__(256) void k_bucket2(const int2* __restrict__ pairs,
                                                 const int* __restrict__ shard_total,
                                                 int2* __restrict__ pairs2,
                                                 int* __restrict__ sub_total,
                                                 int cap, int cap2, int s2, int ns) {
    __shared__ int cnt[16], base[16];
    int s = blockIdx.x & 15;
    if (s >= ns) return;
    if (threadIdx.x < 16) cnt[threadIdx.x] = 0;
    __syncthreads();
    int cntS  = min(shard_total[s], cap);
    int start = ((blockIdx.x >> 4) * 256 + threadIdx.x) * 4;
    int2 p[4]; int sub[4], rk[4]; int nown = 0;
    const int2* seg = pairs + (size_t)s * cap;
#pragma unroll
    for (int j = 0; j < 4; ++j) {
        int idx = start + j;
        if (idx < cntS) { p[nown] = seg[idx]; ++nown; }
    }
    for (int j = 0; j < nown; ++j) {
        sub[j] = (p[j].x >> s2) & 15;
        rk[j]  = atomicAdd(&cnt[sub[j]], 1);
    }
    __syncthreads();
    if (threadIdx.x < 16 && cnt[threadIdx.x] > 0)
        base[threadIdx.x] = atomicAdd(&sub_total[(s << 4) + threadIdx.x], cnt[threadIdx.x]);
    __syncthreads();
    for (int j = 0; j < nown; ++j) {
        int gs  = (s << 4) + sub[j];
        int pos = base[sub[j]] + rk[j];
        if (pos < cap2) pairs2[(size_t)gs * cap2 + pos] = p[j];
    }
}

// one block per 512-node sub-shard: LDS histogram, sequential degi write
__global__ __launch_bounds__(256) void k_hist_sub(const int2* __restrict__ pairs2,
                                                  const int* __restrict__ sub_total,
                                                  int* __restrict__ degi,
                                                  int cap2, int s2, int n, int nsub) {
    extern __shared__ int lcnt[];  // SUBN ints
    int s = blockIdx.x;
    if (s >= nsub) return;
    int SUBN = 1 << s2;
    int lo   = s << s2;
    int nloc = min(SUBN, n - lo);
    for (int t = threadIdx.x; t < nloc; t += 256) lcnt[t] = 0;
    __syncthreads();
    int cnt = min(sub_total[s], cap2);
    const int2* seg = pairs2 + (size_t)s * cap2;
    for (int i = threadIdx.x; i < cnt; i += 256)
        atomicAdd(&lcnt[seg[i].x - lo], 1);
    __syncthreads();
    for (int t = threadIdx.x; t < nloc; t += 256) degi[lo + t] = lcnt[t];
}

// one block per sub-shard: LDS cursors + LDS sort buffer, sequential col write
__global__ __launch_bounds__(256) void k_fill_sub(const int2* __restrict__ pairs2,
                                                  const int* __restrict__ sub_total,
                                                  const int* __restrict__ rowptr,
                                                  int* __restrict__ col,
                                                  int cap2, int s2, int n, int nsub) {
    extern __shared__ int sm[];  // [SUBN cursors][cap2 buffer]
    int s = blockIdx.x;
    if (s >= nsub) return;
    int  SUBN = 1 << s2;
    int* cur  = sm;
    int* buf  = sm + SUBN;
    int  lo   = s << s2;
    int  nloc = min(SUBN, n - lo);
    int  base = rowptr[lo];
    for (int t = threadIdx.x; t < nloc; t += 256) cur[t] = rowptr[lo + t] - base;
    __syncthreads();
    int cnt = min(sub_total[s], cap2);
    const int2* seg = pairs2 + (size_t)s * cap2;
    for (int i = threadIdx.x; i < cnt; i += 256) {
        int2 p  = seg[i];
        int pos = atomicAdd(&cur[p.x - lo], 1);
        if (pos < cap2) buf[pos] = p.y;
    }
    __syncthreads();
    for (int i = threadIdx.x; i < cnt; i += 256) col[base + i] = buf[i];
}

// Per-block exclusive scan of 1024 elements (256 thr x 4), also computes
// dis[v] = rsqrt(deg_real + 1)  (the +1 is the self-loop).
__global__ __launch_bounds__(256) void k_scan_local(const int* __restrict__ degi,
                                                    int* __restrict__ rowptr,
                                                    int* __restrict__ blocksums,
                                                    float* __restrict__ dis, int n) {
    __shared__ int sd[256];
    int tid  = threadIdx.x;
    int base = blockIdx.x * 1024 + tid * 4;
    int v0 = 0, v1 = 0, v2 = 0, v3 = 0;
    if (base + 0 < n) v0 = degi[base + 0];
    if (base + 1 < n) v1 = degi[base + 1];
    if (base + 2 < n) v2 = degi[base + 2];
    if (base + 3 < n) v3 = degi[base + 3];
    if (base + 0 < n) dis[base + 0] = rsqrtf((float)(v0 + 1));
    if (base + 1 < n) dis[base + 1] = rsqrtf((float)(v1 + 1));
    if (base + 2 < n) dis[base + 2] = rsqrtf((float)(v2 + 1));
    if (base + 3 < n) dis[base + 3] = rsqrtf((float)(v3 + 1));
    int tsum = v0 + v1 + v2 + v3;
    sd[tid] = tsum;
    __syncthreads();
    for (int off = 1; off < 256; off <<= 1) {
        int add = (tid >= off) ? sd[tid - off] : 0;
        __syncthreads();
        sd[tid] += add;
        __syncthreads();
    }
    int incl = sd[tid];
    int excl = incl - tsum;
    if (tid == 255) blocksums[blockIdx.x] = incl;
    if (base + 0 < n) rowptr[base + 0] = excl;
    if (base + 1 < n) rowptr[base + 1] = excl + v0;
    if (base + 2 < n) rowptr[base + 2] = excl + v0 + v1;
    if (base + 3 < n) rowptr[base + 3] = excl + v0 + v1 + v2;
}

__global__ __launch_bounds__(128) void k_scan_bsum(int* __restrict__ bs, int nb) {
    __shared__ int sd[128];
    int t = threadIdx.x;
    int v = (t < nb) ? bs[t] : 0;
    sd[t] = v;
    __syncthreads();
    for (int off = 1; off < 128; off <<= 1) {
        int add = (t >= off) ? sd[t - off] : 0;
        __syncthreads();
        sd[t] += add;
        __syncthreads();
    }
    if (t < nb) bs[t] = sd[t] - v;  // exclusive
}

__global__ __launch_bounds__(256) void k_scan_add(int* __restrict__ rowptr,
                                                  const int* __restrict__ blocksums,
                                                  int n, int total) {
    int i = blockIdx.x * 256 + threadIdx.x;
    if (i < n) rowptr[i] += blocksums[i >> 10];
    if (i == 0) rowptr[n] = total;
}

// ---------------------------------------------------------------------------
// h_bf16 = bf16( dis[v] * (x @ W[l]) ).
// W (64KB fp32) + 32-row x tile (16KB) in LDS -> 80KB, 2 blocks/CU.
// Thread computes 4 rows x 4 cols (float4 acc): per k4 the wave issues
// 4 x-reads + 4 W-reads (all ds_read_b128, 2-way broadcast = free) feeding
// 128 FMAs/thread -> VALU-bound. Register-prefetch double buffer.
// ---------------------------------------------------------------------------
__global__ __launch_bounds__(256) void k_gemm(const float* __restrict__ x,
                                              const float* __restrict__ W,
                                              const float* __restrict__ dis,
                                              unsigned short* __restrict__ h, int n) {
    extern __shared__ float smem[];
    float4* Ws4 = (float4*)smem;            // [128 k][32 col-groups]
    float4* xs4 = (float4*)(smem + D * D);  // [32 rows][32 k-groups]
    {
        const float4* W4 = (const float4*)W;
#pragma unroll
        for (int i = 0; i < 16; ++i)
            Ws4[threadIdx.x + i * 256] = W4[threadIdx.x + i * 256];
    }
    int wave  = threadIdx.x >> 6;
    int lane  = threadIdx.x & 63;
    int rbase = wave * 8 + (lane >> 5) * 4;  // local row base (4 rows)
    int cg    = lane & 31;                   // col-group (4 cols)

    const float4* X4 = (const float4*)x;
    size_t n4     = (size_t)n * (D / 4);
    int    ntiles = (n + 31) / 32;

    int    tile = blockIdx.x;
    float4 pf[4];
    {   // prefetch tile 0
        size_t base4 = (size_t)tile * 32 * (D / 4);
#pragma unroll
        for (int j = 0; j < 4; ++j) {
            size_t gi = base4 + threadIdx.x + j * 256;
            pf[j] = (tile < ntiles && gi < n4) ? X4[gi] : float4{0.f, 0.f, 0.f, 0.f};
        }
    }
    __syncthreads();  // W staged

    for (; tile < ntiles; tile += gridDim.x) {
#pragma unroll
        for (int j = 0; j < 4; ++j) xs4[threadIdx.x + j * 256] = pf[j];
        __syncthreads();

        int nt = tile + gridDim.x;  // issue next tile's loads (in flight all compute)
        if (nt < ntiles) {
            size_t base4 = (size_t)nt * 32 * (D / 4);
#pragma unroll
            for (int j = 0; j < 4; ++j) {
                size_t gi = base4 + threadIdx.x + j * 256;
                if (gi < n4) pf[j] = X4[gi];
            }
        }

        float4 acc[4];
#pragma unroll
        for (int r = 0; r < 4; ++r) acc[r] = float4{0.f, 0.f, 0.f, 0.f};

#pragma unroll 4
        for (int k4 = 0; k4 < 32; ++k4) {
            float4 xr[4];
#pragma unroll
            for (int r = 0; r < 4; ++r) xr[r] = xs4[(rbase + r) * 32 + k4];
            float4 wv[4];
#pragma unroll
            for (int i = 0; i < 4; ++i) wv[i] = Ws4[(4 * k4 + i) * 32 + cg];
#pragma unroll
            for (int i = 0; i < 4; ++i) {
#pragma unroll
                for (int r = 0; r < 4; ++r) {
                    float e = (&xr[r].x)[i];
                    acc[r].x = fmaf(e, wv[i].x, acc[r].x);
                    acc[r].y = fmaf(e, wv[i].y, acc[r].y);
                    acc[r].z = fmaf(e, wv[i].z, acc[r].z);
                    acc[r].w = fmaf(e, wv[i].w, acc[r].w);
                }
            }
        }

        int grow = tile * 32 + rbase;
        ushort4* h4 = (ushort4*)h;  // row = 32 ushort4 (4 bf16 each)
#pragma unroll
        for (int r = 0; r < 4; ++r) {
            int row = grow + r;
            if (row < n) {
                float dv = dis[row];
                ushort4 o;
                o.x = f2bf(acc[r].x * dv);
                o.y = f2bf(acc[r].y * dv);
                o.z = f2bf(acc[r].z * dv);
                o.w = f2bf(acc[r].w * dv);
                h4[(size_t)row * 32 + cg] = o;
            }
        }
        __syncthreads();  // xs free for next iteration's store
    }
}

// ---------------------------------------------------------------------------
// out[v] = relu( dis[v] * (hs[v] + sum_{s in N(v)} hs[s]) + b )
// h is bf16: row = 256B = 32 lanes x ushort4. Half-wave per node, 2 nodes per
// wave, 8-deep unrolled gather (2KB in flight per half-wave). fp32 accum.
// ---------------------------------------------------------------------------
__global__ __launch_bounds__(256) void k_agg(const unsigned short* __restrict__ h,
                                             const int* __restrict__ rowptr,
                                             const int* __restrict__ col,
                                             const float* __restrict__ dis,
                                             const float* __restrict__ b,
                                             float* __restrict__ out, int n) {
    int wave = threadIdx.x >> 6;
    int lane = threadIdx.x & 63;
    int half = lane >> 5;
    int hl   = lane & 31;
    int v = blockIdx.x * 8 + wave * 2 + half;
    if (v >= n) return;
    const ushort4* h4 = (const ushort4*)h;  // row = 32 ushort4

    ushort4 sv = h4[(size_t)v * 32 + hl];
    float ax[4] = {bf2f(sv.x), 0.f, 0.f, 0.f};
    float ay[4] = {bf2f(sv.y), 0.f, 0.f, 0.f};
    float az[4] = {bf2f(sv.z), 0.f, 0.f, 0.f};
    float aw[4] = {bf2f(sv.w), 0.f, 0.f, 0.f};

    int beg = rowptr[v], end = rowptr[v + 1];
    int i = beg;
    for (; i + 8 <= end; i += 8) {
        int c[8];
#pragma unroll
        for (int j = 0; j < 8; ++j) c[j] = col[i + j];
        ushort4 m[8];
#pragma unroll
        for (int j = 0; j < 8; ++j) m[j] = h4[(size_t)c[j] * 32 + hl];
#pragma unroll
        for (int j = 0; j < 8; ++j) {
            int q = j & 3;
            ax[q] += bf2f(m[j].x);
            ay[q] += bf2f(m[j].y);
            az[q] += bf2f(m[j].z);
            aw[q] += bf2f(m[j].w);
        }
    }
    for (; i < end; ++i) {
        ushort4 m = h4[(size_t)col[i] * 32 + hl];
        ax[0] += bf2f(m.x); ay[0] += bf2f(m.y);
        az[0] += bf2f(m.z); aw[0] += bf2f(m.w);
    }

    float  dv = dis[v];
    float4 bb = ((const float4*)b)[hl];
    float4 r;
    r.x = fmaxf(0.f, (ax[0] + ax[1] + ax[2] + ax[3]) * dv + bb.x);
    r.y = fmaxf(0.f, (ay[0] + ay[1] + ay[2] + ay[3]) * dv + bb.y);
    r.z = fmaxf(0.f, (az[0] + az[1] + az[2] + az[3]) * dv + bb.z);
    r.w = fmaxf(0.f, (aw[0] + aw[1] + aw[2] + aw[3]) * dv + bb.w);
    ((float4*)out)[(size_t)v * 32 + hl] = r;
}

// ---------------------------------------------------------------------------

extern "C" void kernel_launch(void* const* d_in, const int* in_sizes, int n_in,
                              void* d_out, int out_size, void* d_ws, size_t ws_size,
                              hipStream_t stream) {
    const float* x0 = (const float*)d_in[0];
    const int*   ei = (const int*)d_in[1];
    const float* W  = (const float*)d_in[2];
    const float* b  = (const float*)d_in[3];

    int n = in_sizes[0] / D;        // 100000
    int e = in_sizes[1] / 2;        // 1600000
    int L = in_sizes[2] / (D * D);  // 3

    const int* srcI = ei;       // edge_index[0] : message source
    const int* dstI = ei + e;   // edge_index[1] : aggregation target

    // shard geometry: level-1 shard = dst >> shift (<=16), sub = dst >> s2
    int shift = 13;
    while (((n - 1) >> shift) >= 16) ++shift;
    int ns   = ((n - 1) >> shift) + 1;                            // 13
    int cap  = (int)(((long long)e << shift) / (long long)n) + 32768;
    int s2   = shift - 4;                                         // 9 -> SUBN=512
    int SUBN = 1 << s2;
    int nsub = ((n - 1) >> s2) + 1;                               // 196
    int cap2 = (int)(((long long)e << s2) / (long long)n) + 2048; // 10240

    // workspace carve. pairs2 ALIASES H (CSR build completes before gemm).
    unsigned short* H = (unsigned short*)d_ws;            // n*128 bf16 (25.6MB)
    int*   degi        = (int*)(H + (size_t)n * D);       // n
    int*   shard_total = degi + n;                        // 16
    int*   sub_total   = shard_total + 16;                // nsub
    int*   rowptr      = sub_total + nsub;                // n+1
    float* dis         = (float*)(rowptr + n + 1);        // n
    int*   col         = (int*)(dis + n);                 // e
    int*   blocksums   = col + e;                         // 128
    size_t pa = ((size_t)(blocksums + 128) + 15) & ~(size_t)15;
    int2*  pairs       = (int2*)pa;                       // 16*cap int2 (~21MB)
    int2*  pairs2      = (int2*)H;                        // nsub*cap2 int2 (~16MB)

    hipMemsetAsync(shard_total, 0, (size_t)(16 + nsub) * sizeof(int), stream);

    int nblA = ((e + 3) / 4 + 255) / 256;
    k_bucket<<<nblA, 256, 0, stream>>>(dstI, srcI, pairs, shard_total, e, shift, cap);

    int bps2 = (cap + 1023) / 1024;
    k_bucket2<<<16 * bps2, 256, 0, stream>>>(pairs, shard_total, pairs2, sub_total,
                                             cap, cap2, s2, ns);

    k_hist_sub<<<nsub, 256, (size_t)SUBN * 4, stream>>>(pairs2, sub_total, degi,
                                                        cap2, s2, n, nsub);

    int nscan = (n + 1023) / 1024;
    k_scan_local<<<nscan, 256, 0, stream>>>(degi, rowptr, blocksums, dis, n);
    k_scan_bsum<<<1, 128, 0, stream>>>(blocksums, nscan);
    int nb2 = (n + 255) / 256;
    k_scan_add<<<nb2, 256, 0, stream>>>(rowptr, blocksums, n, e);

    k_fill_sub<<<nsub, 256, (size_t)(SUBN + cap2) * 4, stream>>>(pairs2, sub_total,
                                                                 rowptr, col, cap2,
                                                                 s2, n, nsub);

    float*       out = (float*)d_out;
    const float* xin = x0;
    size_t lds_bytes = (size_t)(D * D + 32 * D) * sizeof(float);  // 80 KB
    for (int l = 0; l < L; ++l) {
        k_gemm<<<512, 256, lds_bytes, stream>>>(xin, W + (size_t)l * D * D, dis, H, n);
        k_agg<<<(n + 7) / 8, 256, 0, stream>>>(H, rowptr, col, dis, b + (size_t)l * D, out, n);
        xin = out;
    }
}

// Round 12
// 443.920 us; speedup vs baseline: 1.4469x; 1.2223x over previous
//
#include <hip/hip_runtime.h>

#define D 128

typedef __attribute__((ext_vector_type(8))) short short8v;
typedef __attribute__((ext_vector_type(4))) float float4v;

__device__ __forceinline__ unsigned short f2bf(float f) {
    union { float f; unsigned u; } c; c.f = f;
    unsigned u = c.u;
    return (unsigned short)((u + 0x7fffu + ((u >> 16) & 1u)) >> 16);  // RNE
}
__device__ __forceinline__ float bf2f(unsigned short s) {
    union { unsigned u; float f; } c; c.u = ((unsigned)s) << 16;
    return c.f;
}

// ---------------------------------------------------------------------------
// CSR build (unchanged from round 11): two-level bucketize + LDS-local
// hist/fill; no global random scatter anywhere.
// ---------------------------------------------------------------------------

__global__ __launch_bounds__(256) void k_bucket(const int* __restrict__ dst,
                                                const int* __restrict__ src,
                                                int2* __restrict__ pairs,
                                                int* __restrict__ shard_total,
                                                int e, int shift, int cap) {
    __shared__ int cnt[16], base[16];
    if (threadIdx.x < 16) cnt[threadIdx.x] = 0;
    __syncthreads();
    int i4    = blockIdx.x * 256 + threadIdx.x;
    int ebase = i4 * 4;
    int nown  = min(4, e - ebase);  // may be <=0
    int dd[4], ss[4], sh[4], rk[4];
    if (nown == 4) {
        int4 d = ((const int4*)dst)[i4];
        int4 s = ((const int4*)src)[i4];
        dd[0] = d.x; dd[1] = d.y; dd[2] = d.z; dd[3] = d.w;
        ss[0] = s.x; ss[1] = s.y; ss[2] = s.z; ss[3] = s.w;
    } else {
        for (int j = 0; j < nown; ++j) { dd[j] = dst[ebase + j]; ss[j] = src[ebase + j]; }
    }
    for (int j = 0; j < nown; ++j) {
        sh[j] = dd[j] >> shift;
        rk[j] = atomicAdd(&cnt[sh[j]], 1);
    }
    __syncthreads();
    if (threadIdx.x < 16 && cnt[threadIdx.x] > 0)
        base[threadIdx.x] = atomicAdd(&shard_total[threadIdx.x], cnt[threadIdx.x]);
    __syncthreads();
    for (int j = 0; j < nown; ++j) {
        int pos = base[sh[j]] + rk[j];
        if (pos < cap) pairs[(size_t)sh[j] * cap + pos] = int2{dd[j], ss[j]};
    }
}

__global__ __launch_bounds__(256) void k_bucket2(const int2* __restrict__ pairs,
                                                 const int* __restrict__ shard_total,
                                                 int2* __restrict__ pairs2,
                                                 int* __restrict__ sub_total,
                                                 int cap, int cap2, int s2, int ns) {
    __shared__ int cnt[16], base[16];
    int s = blockIdx.x & 15;
    if (s >= ns) return;
    if (threadIdx.x < 16) cnt[threadIdx.x] = 0;
    __syncthreads();
    int cntS  = min(shard_total[s], cap);
    int start = ((blockIdx.x >> 4) * 256 + threadIdx.x) * 4;
    int2 p[4]; int sub[4], rk[4]; int nown = 0;
    const int2* seg = pairs + (size_t)s * cap;
#pragma unroll
    for (int j = 0; j < 4; ++j) {
        int idx = start + j;
        if (idx < cntS) { p[nown] = seg[idx]; ++nown; }
    }
    for (int j = 0; j < nown; ++j) {
        sub[j] = (p[j].x >> s2) & 15;
        rk[j]  = atomicAdd(&cnt[sub[j]], 1);
    }
    __syncthreads();
    if (threadIdx.x < 16 && cnt[threadIdx.x] > 0)
        base[threadIdx.x] = atomicAdd(&sub_total[(s << 4) + threadIdx.x], cnt[threadIdx.x]);
    __syncthreads();
    for (int j = 0; j < nown; ++j) {
        int gs  = (s << 4) + sub[j];
        int pos = base[sub[j]] + rk[j];
        if (pos < cap2) pairs2[(size_t)gs * cap2 + pos] = p[j];
    }
}

__global__ __launch_bounds__(256) void k_hist_sub(const int2* __restrict__ pairs2,
                                                  const int* __restrict__ sub_total,
                                                  int* __restrict__ degi,
                                                  int cap2, int s2, int n, int nsub) {
    extern __shared__ int lcnt[];
    int s = blockIdx.x;
    if (s >= nsub) return;
    int SUBN = 1 << s2;
    int lo   = s << s2;
    int nloc = min(SUBN, n - lo);
    for (int t = threadIdx.x; t < nloc; t += 256) lcnt[t] = 0;
    __syncthreads();
    int cnt = min(sub_total[s], cap2);
    const int2* seg = pairs2 + (size_t)s * cap2;
    for (int i = threadIdx.x; i < cnt; i += 256)
        atomicAdd(&lcnt[seg[i].x - lo], 1);
    __syncthreads();
    for (int t = threadIdx.x; t < nloc; t += 256) degi[lo + t] = lcnt[t];
}

__global__ __launch_bounds__(256) void k_fill_sub(const int2* __restrict__ pairs2,
                                                  const int* __restrict__ sub_total,
                                                  const int* __restrict__ rowptr,
                                                  int* __restrict__ col,
                                                  int cap2, int s2, int n, int nsub) {
    extern __shared__ int sm[];
    int s = blockIdx.x;
    if (s >= nsub) return;
    int  SUBN = 1 << s2;
    int* cur  = sm;
    int* buf  = sm + SUBN;
    int  lo   = s << s2;
    int  nloc = min(SUBN, n - lo);
    int  base = rowptr[lo];
    for (int t = threadIdx.x; t < nloc; t += 256) cur[t] = rowptr[lo + t] - base;
    __syncthreads();
    int cnt = min(sub_total[s], cap2);
    const int2* seg = pairs2 + (size_t)s * cap2;
    for (int i = threadIdx.x; i < cnt; i += 256) {
        int2 p  = seg[i];
        int pos = atomicAdd(&cur[p.x - lo], 1);
        if (pos < cap2) buf[pos] = p.y;
    }
    __syncthreads();
    for (int i = threadIdx.x; i < cnt; i += 256) col[base + i] = buf[i];
}

__global__ __launch_bounds__(256) void k_scan_local(const int* __restrict__ degi,
                                                    int* __restrict__ rowptr,
                                                    int* __restrict__ blocksums,
                                                    float* __restrict__ dis, int n) {
    __shared__ int sd[256];
    int tid  = threadIdx.x;
    int base = blockIdx.x * 1024 + tid * 4;
    int v0 = 0, v1 = 0, v2 = 0, v3 = 0;
    if (base + 0 < n) v0 = degi[base + 0];
    if (base + 1 < n) v1 = degi[base + 1];
    if (base + 2 < n) v2 = degi[base + 2];
    if (base + 3 < n) v3 = degi[base + 3];
    if (base + 0 < n) dis[base + 0] = rsqrtf((float)(v0 + 1));
    if (base + 1 < n) dis[base + 1] = rsqrtf((float)(v1 + 1));
    if (base + 2 < n) dis[base + 2] = rsqrtf((float)(v2 + 1));
    if (base + 3 < n) dis[base + 3] = rsqrtf((float)(v3 + 1));
    int tsum = v0 + v1 + v2 + v3;
    sd[tid] = tsum;
    __syncthreads();
    for (int off = 1; off < 256; off <<= 1) {
        int add = (tid >= off) ? sd[tid - off] : 0;
        __syncthreads();
        sd[tid] += add;
        __syncthreads();
    }
    int incl = sd[tid];
    int excl = incl - tsum;
    if (tid == 255) blocksums[blockIdx.x] = incl;
    if (base + 0 < n) rowptr[base + 0] = excl;
    if (base + 1 < n) rowptr[base + 1] = excl + v0;
    if (base + 2 < n) rowptr[base + 2] = excl + v0 + v1;
    if (base + 3 < n) rowptr[base + 3] = excl + v0 + v1 + v2;
}

__global__ __launch_bounds__(128) void k_scan_bsum(int* __restrict__ bs, int nb) {
    __shared__ int sd[128];
    int t = threadIdx.x;
    int v = (t < nb) ? bs[t] : 0;
    sd[t] = v;
    __syncthreads();
    for (int off = 1; off < 128; off <<= 1) {
        int add = (t >= off) ? sd[t - off] : 0;
        __syncthreads();
        sd[t] += add;
        __syncthreads();
    }
    if (t < nb) bs[t] = sd[t] - v;  // exclusive
}

__global__ __launch_bounds__(256) void k_scan_add(int* __restrict__ rowptr,
                                                  const int* __restrict__ blocksums,
                                                  int n, int total) {
    int i = blockIdx.x * 256 + threadIdx.x;
    if (i < n) rowptr[i] += blocksums[i >> 10];
    if (i == 0) rowptr[n] = total;
}

// ---------------------------------------------------------------------------
// W [L][k][n] fp32  ->  WT [L][n][k] bf16 (for contiguous-k B fragments).
// ---------------------------------------------------------------------------
__global__ __launch_bounds__(256) void k_prepW(const float* __restrict__ W,
                                               unsigned short* __restrict__ WT,
                                               int total) {
    int i = blockIdx.x * 256 + threadIdx.x;
    if (i < total) {
        int l = i >> 14, rem = i & 16383, nn = rem >> 7, kk = rem & 127;
        WT[i] = f2bf(W[(l << 14) + kk * D + nn]);
    }
}

// ---------------------------------------------------------------------------
// h_bf16 = bf16( dis[row] * (x @ W) ) via mfma_f32_16x16x32_bf16.
// No LDS. Per wave: one 16-row stripe x 128 cols = 8 n-tiles; K=128 = 4 steps.
// All 32 B-fragments (W^T) register-resident (128 VGPR); A-fragments loaded
// global->reg (16B contiguous per lane); next stripe's A prefetched under the
// 32 MFMAs. A/B k-ordering is consistent-contiguous (permutation-invariant);
// C/D layout: col=lane&15, row=(lane>>4)*4+reg (HW-verified).
// ---------------------------------------------------------------------------
template<bool XF32>
__global__ __launch_bounds__(256) void k_gemm_mfma(const void* __restrict__ xin,
                                                   const unsigned short* __restrict__ WT,
                                                   const float* __restrict__ dis,
                                                   unsigned short* __restrict__ h,
                                                   int n) {
    int lane = threadIdx.x & 63;
    int g    = lane >> 4;   // k-group
    int r16  = lane & 15;   // A-row / B-col within tile
    int gw   = blockIdx.x * 4 + (threadIdx.x >> 6);
    int nw   = gridDim.x * 4;

    short8v bfr[8][4];  // [n-tile][k-step]
#pragma unroll
    for (int t = 0; t < 8; ++t)
#pragma unroll
        for (int kk = 0; kk < 4; ++kk)
            bfr[t][kk] = *(const short8v*)(WT + (size_t)(t * 16 + r16) * D + kk * 32 + g * 8);

    int nstripes = (n + 15) >> 4;
    if (gw >= nstripes) return;

    auto loadA = [&](int s, short8v a[4]) {
        int row = s * 16 + r16;
        if (row >= n) row = n - 1;
        if constexpr (XF32) {
            const float* xf = (const float*)xin + (size_t)row * D;
#pragma unroll
            for (int kk = 0; kk < 4; ++kk) {
                float4 lo = *(const float4*)(xf + kk * 32 + g * 8);
                float4 hi = *(const float4*)(xf + kk * 32 + g * 8 + 4);
                short8v v;
                v[0] = (short)f2bf(lo.x); v[1] = (short)f2bf(lo.y);
                v[2] = (short)f2bf(lo.z); v[3] = (short)f2bf(lo.w);
                v[4] = (short)f2bf(hi.x); v[5] = (short)f2bf(hi.y);
                v[6] = (short)f2bf(hi.z); v[7] = (short)f2bf(hi.w);
                a[kk] = v;
            }
        } else {
            const unsigned short* xb = (const unsigned short*)xin + (size_t)row * D;
#pragma unroll
            for (int kk = 0; kk < 4; ++kk)
                a[kk] = *(const short8v*)(xb + kk * 32 + g * 8);
        }
    };

    short8v cur[4], nxt[4];
    loadA(gw, cur);
    for (int s = gw; s < nstripes; s += nw) {
        int sn = s + nw;
        if (sn < nstripes) loadA(sn, nxt);

        float4v acc[8];
        float4v z = {0.f, 0.f, 0.f, 0.f};
#pragma unroll
        for (int t = 0; t < 8; ++t) acc[t] = z;
#pragma unroll
        for (int kk = 0; kk < 4; ++kk)
#pragma unroll
            for (int t = 0; t < 8; ++t)
                acc[t] = __builtin_amdgcn_mfma_f32_16x16x32_bf16(cur[kk], bfr[t][kk],
                                                                 acc[t], 0, 0, 0);

        int orow0 = s * 16 + g * 4;
        float4 dv = *(const float4*)(dis + orow0);  // in ws, safe even at tail
#pragma unroll
        for (int rg = 0; rg < 4; ++rg) {
            int orow = orow0 + rg;
            if (orow < n) {
                float dvv = (&dv.x)[rg];
                unsigned short* hp = h + (size_t)orow * D + r16;
#pragma unroll
                for (int t = 0; t < 8; ++t)
                    hp[t * 16] = f2bf(acc[t][rg] * dvv);
            }
        }
#pragma unroll
        for (int kk = 0; kk < 4; ++kk) cur[kk] = nxt[kk];
    }
}

// ---------------------------------------------------------------------------
// out[v] = relu( dis[v] * (hs[v] + sum_{s in N(v)} hs[s]) + b )
// Half-wave per node, 8-deep unrolled ushort4 gather, fp32 accum.
// BF16OUT: intermediate layers write bf16 activations (next gemm input).
// ---------------------------------------------------------------------------
template<bool BF16OUT>
__global__ __launch_bounds__(256) void k_agg(const unsigned short* __restrict__ h,
                                             const int* __restrict__ rowptr,
                                             const int* __restrict__ col,
                                             const float* __restrict__ dis,
                                             const float* __restrict__ b,
                                             void* __restrict__ out, int n) {
    int wave = threadIdx.x >> 6;
    int lane = threadIdx.x & 63;
    int half = lane >> 5;
    int hl   = lane & 31;
    int v = blockIdx.x * 8 + wave * 2 + half;
    if (v >= n) return;
    const ushort4* h4 = (const ushort4*)h;

    ushort4 sv = h4[(size_t)v * 32 + hl];
    float ax[4] = {bf2f(sv.x), 0.f, 0.f, 0.f};
    float ay[4] = {bf2f(sv.y), 0.f, 0.f, 0.f};
    float az[4] = {bf2f(sv.z), 0.f, 0.f, 0.f};
    float aw[4] = {bf2f(sv.w), 0.f, 0.f, 0.f};

    int beg = rowptr[v], end = rowptr[v + 1];
    int i = beg;
    for (; i + 8 <= end; i += 8) {
        int c[8];
#pragma unroll
        for (int j = 0; j < 8; ++j) c[j] = col[i + j];
        ushort4 m[8];
#pragma unroll
        for (int j = 0; j < 8; ++j) m[j] = h4[(size_t)c[j] * 32 + hl];
#pragma unroll
        for (int j = 0; j < 8; ++j) {
            int q = j & 3;
            ax[q] += bf2f(m[j].x);
            ay[q] += bf2f(m[j].y);
            az[q] += bf2f(m[j].z);
            aw[q] += bf2f(m[j].w);
        }
    }
    for (; i < end; ++i) {
        ushort4 m = h4[(size_t)col[i] * 32 + hl];
        ax[0] += bf2f(m.x); ay[0] += bf2f(m.y);
        az[0] += bf2f(m.z); aw[0] += bf2f(m.w);
    }

    float  dv = dis[v];
    float4 bb = ((const float4*)b)[hl];
    float rx = fmaxf(0.f, (ax[0] + ax[1] + ax[2] + ax[3]) * dv + bb.x);
    float ry = fmaxf(0.f, (ay[0] + ay[1] + ay[2] + ay[3]) * dv + bb.y);
    float rz = fmaxf(0.f, (az[0] + az[1] + az[2] + az[3]) * dv + bb.z);
    float rw = fmaxf(0.f, (aw[0] + aw[1] + aw[2] + aw[3]) * dv + bb.w);
    if (BF16OUT) {
        ushort4 o;
        o.x = f2bf(rx); o.y = f2bf(ry); o.z = f2bf(rz); o.w = f2bf(rw);
        ((ushort4*)out)[(size_t)v * 32 + hl] = o;
    } else {
        float4 o; o.x = rx; o.y = ry; o.z = rz; o.w = rw;
        ((float4*)out)[(size_t)v * 32 + hl] = o;
    }
}

// ---------------------------------------------------------------------------

extern "C" void kernel_launch(void* const* d_in, const int* in_sizes, int n_in,
                              void* d_out, int out_size, void* d_ws, size_t ws_size,
                              hipStream_t stream) {
    const float* x0 = (const float*)d_in[0];
    const int*   ei = (const int*)d_in[1];
    const float* W  = (const float*)d_in[2];
    const float* b  = (const float*)d_in[3];

    int n = in_sizes[0] / D;        // 100000
    int e = in_sizes[1] / 2;        // 1600000
    int L = in_sizes[2] / (D * D);  // 3

    const int* srcI = ei;       // edge_index[0] : message source
    const int* dstI = ei + e;   // edge_index[1] : aggregation target

    // shard geometry
    int shift = 13;
    while (((n - 1) >> shift) >= 16) ++shift;
    int ns   = ((n - 1) >> shift) + 1;
    int cap  = (int)(((long long)e << shift) / (long long)n) + 32768;
    int s2   = shift - 4;
    int SUBN = 1 << s2;
    int nsub = ((n - 1) >> s2) + 1;
    int cap2 = (int)(((long long)e << s2) / (long long)n) + 2048;

    // ---- workspace carve (16B-aligned regions; aliasing is stream-ordered):
    //   pairs2 aliases H  (pairs2 dead before first gemm writes H)
    //   pairs  aliases XB (pairs dead before first agg writes XB)
    auto al16 = [](size_t x) { return (x + 15) & ~(size_t)15; };
    size_t szH  = al16((size_t)n * D * 2);
    size_t szP  = al16((size_t)16 * cap * 8);
    size_t szXB = al16((size_t)n * D * 2);
    size_t szR1 = szP > szXB ? szP : szXB;

    char* p = (char*)d_ws;
    unsigned short* H  = (unsigned short*)p; p += szH;
    char*           R1 = p;                  p += szR1;
    int*   degi        = (int*)p;            p += al16((size_t)n * 4);
    int*   shard_total = (int*)p;            p += al16((size_t)16 * 4);
    int*   sub_total   = (int*)p;            p += al16((size_t)nsub * 4);
    int*   rowptr      = (int*)p;            p += al16((size_t)(n + 1) * 4);
    int*   blocksums   = (int*)p;            p += al16((size_t)128 * 4);
    float* dis         = (float*)p;          p += al16((size_t)n * 4);
    int*   col         = (int*)p;            p += al16((size_t)e * 4);
    unsigned short* WT = (unsigned short*)p; p += al16((size_t)L * D * D * 2);

    int2* pairs  = (int2*)R1;
    int2* pairs2 = (int2*)H;
    unsigned short* XB = (unsigned short*)R1;

    hipMemsetAsync(shard_total, 0, (size_t)(16 + nsub) * sizeof(int), stream);

    int nblA = ((e + 3) / 4 + 255) / 256;
    k_bucket<<<nblA, 256, 0, stream>>>(dstI, srcI, pairs, shard_total, e, shift, cap);

    int bps2 = (cap + 1023) / 1024;
    k_bucket2<<<16 * bps2, 256, 0, stream>>>(pairs, shard_total, pairs2, sub_total,
                                             cap, cap2, s2, ns);

    k_hist_sub<<<nsub, 256, (size_t)SUBN * 4, stream>>>(pairs2, sub_total, degi,
                                                        cap2, s2, n, nsub);

    int nscan = (n + 1023) / 1024;
    k_scan_local<<<nscan, 256, 0, stream>>>(degi, rowptr, blocksums, dis, n);
    k_scan_bsum<<<1, 128, 0, stream>>>(blocksums, nscan);
    int nb2 = (n + 255) / 256;
    k_scan_add<<<nb2, 256, 0, stream>>>(rowptr, blocksums, n, e);

    k_fill_sub<<<nsub, 256, (size_t)(SUBN + cap2) * 4, stream>>>(pairs2, sub_total,
                                                                 rowptr, col, cap2,
                                                                 s2, n, nsub);

    int wtot = L * D * D;
    k_prepW<<<(wtot + 255) / 256, 256, 0, stream>>>(W, WT, wtot);

    int aggb = (n + 7) / 8;
    // layer 0: fp32 x0 -> H; agg -> bf16 XB
    k_gemm_mfma<true><<<512, 256, 0, stream>>>(x0, WT, dis, H, n);
    k_agg<true><<<aggb, 256, 0, stream>>>(H, rowptr, col, dis, b, XB, n);
    // layer 1: bf16 XB -> H; agg -> bf16 XB
    k_gemm_mfma<false><<<512, 256, 0, stream>>>(XB, WT + (size_t)D * D, dis, H, n);
    k_agg<true><<<aggb, 256, 0, stream>>>(H, rowptr, col, dis, b + D, XB, n);
    // layer 2: bf16 XB -> H; agg -> fp32 d_out
    k_gemm_mfma<false><<<512, 256, 0, stream>>>(XB, WT + (size_t)2 * D * D, dis, H, n);
    k_agg<false><<<aggb, 256, 0, stream>>>(H, rowptr, col, dis, b + 2 * D, d_out, n);
}